// Round 1
// baseline (1496.699 us; speedup 1.0000x reference)
//
#include <hip/hip_runtime.h>
#include <hip/hip_bf16.h>
#include <cstdint>

#define S_LEN 2048
#define HIDN  2048
#define NH    32
#define NKV   8
#define HD    64
#define FFN   8192

typedef __attribute__((ext_vector_type(4))) float f32x4;
typedef __attribute__((ext_vector_type(8))) short short8;

__device__ __forceinline__ short f2bf(float f) {
  union { float f; uint32_t u; } v; v.f = f;
  uint32_t r = v.u + 0x7FFFu + ((v.u >> 16) & 1u);
  return (short)(r >> 16);
}

// ---------------- RMSNorm (fp32 exact) ----------------
__global__ __launch_bounds__(256) void rmsnorm_kernel(const float* __restrict__ X,
    const float* __restrict__ W, float* __restrict__ Y) {
  int row = blockIdx.x;
  const float4* x4 = (const float4*)(X + (size_t)row * HIDN);
  const float4* w4 = (const float4*)W;
  float4* y4 = (float4*)(Y + (size_t)row * HIDN);
  float4 v0 = x4[threadIdx.x];
  float4 v1 = x4[threadIdx.x + 256];
  float ss = v0.x*v0.x + v0.y*v0.y + v0.z*v0.z + v0.w*v0.w
           + v1.x*v1.x + v1.y*v1.y + v1.z*v1.z + v1.w*v1.w;
  #pragma unroll
  for (int off = 32; off > 0; off >>= 1) ss += __shfl_xor(ss, off, 64);
  __shared__ float red[4];
  if ((threadIdx.x & 63) == 0) red[threadIdx.x >> 6] = ss;
  __syncthreads();
  ss = red[0] + red[1] + red[2] + red[3];
  float rs = rsqrtf(ss * (1.0f / HIDN) + 1e-5f);
  float4 w0 = w4[threadIdx.x], w1 = w4[threadIdx.x + 256];
  float4 o0, o1;
  o0.x = v0.x * rs * w0.x; o0.y = v0.y * rs * w0.y;
  o0.z = v0.z * rs * w0.z; o0.w = v0.w * rs * w0.w;
  o1.x = v1.x * rs * w1.x; o1.y = v1.y * rs * w1.y;
  o1.z = v1.z * rs * w1.z; o1.w = v1.w * rs * w1.w;
  y4[threadIdx.x] = o0;
  y4[threadIdx.x + 256] = o1;
}

// ---------------- GEMM: C[M][N] = A[M][K] @ B[K][N], bf16 MFMA, fp32 acc ----
// EP=0: C=acc  EP=1: C=acc+X  EP=2: C=silu(X)*acc
template<int EP>
__global__ __launch_bounds__(256) void gemm_kernel(const float* __restrict__ A,
    const float* __restrict__ Bw, float* __restrict__ C, const float* __restrict__ X,
    int M, int N, int K) {
  __shared__ __align__(16) short As[128][40];
  __shared__ __align__(16) short Bs[128][40];
  const int tid = threadIdx.x;
  const int lane = tid & 63;
  const int w = tid >> 6;
  const int wm = (w >> 1) * 64, wn = (w & 1) * 64;
  const int l15 = lane & 15, lk = (lane >> 4) * 8;
  f32x4 acc[4][4] = {};
  const int ar = tid >> 1, akh = (tid & 1) * 16;
  const int bkr = tid >> 3, bnh = (tid & 7) * 16;
  const float* Ap = A + (size_t)(blockIdx.x * 128 + ar) * K + akh;
  const float* Bp = Bw + (size_t)bkr * N + blockIdx.y * 128 + bnh;

  for (int k0 = 0; k0 < K; k0 += 32) {
    __syncthreads();
    // stage A tile (128 x 32), K-contiguous in LDS
    float4 a0 = *(const float4*)(Ap + k0);
    float4 a1 = *(const float4*)(Ap + k0 + 4);
    float4 a2 = *(const float4*)(Ap + k0 + 8);
    float4 a3 = *(const float4*)(Ap + k0 + 12);
    short8 pa0, pa1;
    pa0[0]=f2bf(a0.x); pa0[1]=f2bf(a0.y); pa0[2]=f2bf(a0.z); pa0[3]=f2bf(a0.w);
    pa0[4]=f2bf(a1.x); pa0[5]=f2bf(a1.y); pa0[6]=f2bf(a1.z); pa0[7]=f2bf(a1.w);
    pa1[0]=f2bf(a2.x); pa1[1]=f2bf(a2.y); pa1[2]=f2bf(a2.z); pa1[3]=f2bf(a2.w);
    pa1[4]=f2bf(a3.x); pa1[5]=f2bf(a3.y); pa1[6]=f2bf(a3.z); pa1[7]=f2bf(a3.w);
    short8* da = (short8*)&As[ar][akh];
    da[0] = pa0; da[1] = pa1;
    // stage B tile (32 x 128) transposed -> Bs[n][k]
    const float* bp = Bp + (size_t)k0 * N;
    float4 b0 = *(const float4*)(bp);
    float4 b1 = *(const float4*)(bp + 4);
    float4 b2 = *(const float4*)(bp + 8);
    float4 b3 = *(const float4*)(bp + 12);
    float bvl[16] = {b0.x,b0.y,b0.z,b0.w, b1.x,b1.y,b1.z,b1.w,
                     b2.x,b2.y,b2.z,b2.w, b3.x,b3.y,b3.z,b3.w};
    #pragma unroll
    for (int j = 0; j < 16; ++j) Bs[bnh + j][bkr] = f2bf(bvl[j]);
    __syncthreads();
    short8 af[4], bfr[4];
    #pragma unroll
    for (int m = 0; m < 4; ++m) af[m] = *(const short8*)&As[wm + m*16 + l15][lk];
    #pragma unroll
    for (int n = 0; n < 4; ++n) bfr[n] = *(const short8*)&Bs[wn + n*16 + l15][lk];
    #pragma unroll
    for (int m = 0; m < 4; ++m)
      #pragma unroll
      for (int n = 0; n < 4; ++n)
        acc[m][n] = __builtin_amdgcn_mfma_f32_16x16x32_bf16(af[m], bfr[n], acc[m][n], 0, 0, 0);
  }
  const int row0 = blockIdx.x * 128 + wm + (lane >> 4) * 4;
  const int col0 = blockIdx.y * 128 + wn + l15;
  #pragma unroll
  for (int m = 0; m < 4; ++m)
    #pragma unroll
    for (int n = 0; n < 4; ++n)
      #pragma unroll
      for (int i = 0; i < 4; ++i) {
        size_t idx = (size_t)(row0 + m*16 + i) * N + (col0 + n*16);
        float val = acc[m][n][i];
        if (EP == 1) val += X[idx];
        if (EP == 2) { float gg = X[idx]; val *= gg / (1.f + __expf(-gg)); }
        C[idx] = val;
      }
}

// ---------------- RoPE (in-place, q and k) ----------------
__global__ __launch_bounds__(256) void rope_kernel(float* __restrict__ q, float* __restrict__ k,
    const float* __restrict__ cosb, const float* __restrict__ sinb) {
  int idx = blockIdx.x * 256 + threadIdx.x;
  int d = idx & 31;
  int hh = (idx >> 5) % (NH + NKV);
  int s = idx / (32 * (NH + NKV));
  if (s >= S_LEN) return;
  float c  = cosb[s * HD + d];
  float sn = sinb[s * HD + d];
  float* base = (hh < NH) ? (q + (size_t)s * (NH*HD) + hh*HD)
                          : (k + (size_t)s * (NKV*HD) + (hh - NH)*HD);
  float x1 = base[d], x2 = base[d + 32];
  base[d]      = x1 * c - x2 * sn;
  base[d + 32] = x2 * c + x1 * sn;
}

// ---------------- Flash attention (causal, GQA), bf16 MFMA ----------------
__global__ __launch_bounds__(256) void attn_kernel(const float* __restrict__ Q,
    const float* __restrict__ Kb, const float* __restrict__ Vb, float* __restrict__ O) {
  __shared__ __align__(16) short Ks[64][72];
  __shared__ __align__(16) short VTs[64][72];
  __shared__ __align__(16) short Ps[4][16][72];
  const int h  = blockIdx.x >> 5;      // 32 q-tiles per head
  const int qt = blockIdx.x & 31;
  const int kvh = h >> 2;              // N_REP = 4
  const int tid = threadIdx.x, lane = tid & 63, w = tid >> 6;
  const int l15 = lane & 15, lg = lane >> 4;
  const int qr0 = qt * 64 + w * 16;
  // Q fragments (scale 1/8 folded in; exact in bf16)
  short8 aq[2];
  #pragma unroll
  for (int kk = 0; kk < 2; ++kk) {
    const float* qp = Q + (size_t)(qr0 + l15) * (NH*HD) + h*HD + kk*32 + lg*8;
    #pragma unroll
    for (int e = 0; e < 8; ++e) aq[kk][e] = f2bf(qp[e] * 0.125f);
  }
  float m_[4] = {-3e38f, -3e38f, -3e38f, -3e38f};
  float l_[4] = {0.f, 0.f, 0.f, 0.f};
  f32x4 o_[4] = {};
  const int r4 = tid >> 2, ch = (tid & 3) * 16;

  for (int t = 0; t <= qt; ++t) {
    const int kb = t * 64;
    __syncthreads();
    {
      // stage K tile [64][64] (row-major, d-contiguous)
      const float* kp = Kb + (size_t)(kb + r4) * (NKV*HD) + kvh*HD + ch;
      float4 c0 = *(const float4*)(kp);
      float4 c1 = *(const float4*)(kp + 4);
      float4 c2 = *(const float4*)(kp + 8);
      float4 c3 = *(const float4*)(kp + 12);
      short8 k0v, k1v;
      k0v[0]=f2bf(c0.x); k0v[1]=f2bf(c0.y); k0v[2]=f2bf(c0.z); k0v[3]=f2bf(c0.w);
      k0v[4]=f2bf(c1.x); k0v[5]=f2bf(c1.y); k0v[6]=f2bf(c1.z); k0v[7]=f2bf(c1.w);
      k1v[0]=f2bf(c2.x); k1v[1]=f2bf(c2.y); k1v[2]=f2bf(c2.z); k1v[3]=f2bf(c2.w);
      k1v[4]=f2bf(c3.x); k1v[5]=f2bf(c3.y); k1v[6]=f2bf(c3.z); k1v[7]=f2bf(c3.w);
      short8* dk = (short8*)&Ks[r4][ch];
      dk[0] = k0v; dk[1] = k1v;
      // stage V tile transposed -> VTs[d][k]
      const float* vp = Vb + (size_t)(kb + r4) * (NKV*HD) + kvh*HD + ch;
      float4 d0 = *(const float4*)(vp);
      float4 d1 = *(const float4*)(vp + 4);
      float4 d2 = *(const float4*)(vp + 8);
      float4 d3 = *(const float4*)(vp + 12);
      float vvals[16] = {d0.x,d0.y,d0.z,d0.w, d1.x,d1.y,d1.z,d1.w,
                         d2.x,d2.y,d2.z,d2.w, d3.x,d3.y,d3.z,d3.w};
      #pragma unroll
      for (int j = 0; j < 16; ++j) VTs[ch + j][r4] = f2bf(vvals[j]);
    }
    __syncthreads();
    // S = Q @ K^T  (16 q-rows x 64 k-cols per wave)
    f32x4 s[4] = {};
    #pragma unroll
    for (int c = 0; c < 4; ++c)
      #pragma unroll
      for (int kk = 0; kk < 2; ++kk) {
        short8 bk = *(const short8*)&Ks[c*16 + l15][kk*32 + lg*8];
        s[c] = __builtin_amdgcn_mfma_f32_16x16x32_bf16(aq[kk], bk, s[c], 0, 0, 0);
      }
    if (t == qt) {  // diagonal tile: per-element causal mask
      #pragma unroll
      for (int c = 0; c < 4; ++c)
        #pragma unroll
        for (int i = 0; i < 4; ++i) {
          int rq = qr0 + lg*4 + i;
          int ck = kb + c*16 + l15;
          if (ck > rq) s[c][i] = -1e30f;
        }
    }
    // online softmax
    float pm[4], mn[4], al[4];
    #pragma unroll
    for (int i = 0; i < 4; ++i) {
      float vmx = fmaxf(fmaxf(s[0][i], s[1][i]), fmaxf(s[2][i], s[3][i]));
      #pragma unroll
      for (int off = 1; off < 16; off <<= 1) vmx = fmaxf(vmx, __shfl_xor(vmx, off, 16));
      pm[i] = vmx;
      mn[i] = fmaxf(m_[i], pm[i]);
      al[i] = __expf(m_[i] - mn[i]);
    }
    float p[4][4];
    float rs[4] = {0.f, 0.f, 0.f, 0.f};
    #pragma unroll
    for (int c = 0; c < 4; ++c)
      #pragma unroll
      for (int i = 0; i < 4; ++i) { p[c][i] = __expf(s[c][i] - mn[i]); rs[i] += p[c][i]; }
    #pragma unroll
    for (int i = 0; i < 4; ++i) {
      float vsum = rs[i];
      #pragma unroll
      for (int off = 1; off < 16; off <<= 1) vsum += __shfl_xor(vsum, off, 16);
      l_[i] = l_[i] * al[i] + vsum;
      m_[i] = mn[i];
    }
    #pragma unroll
    for (int n = 0; n < 4; ++n)
      #pragma unroll
      for (int i = 0; i < 4; ++i) o_[n][i] *= al[i];
    // P (D-layout) -> LDS -> A-layout fragments (per-wave buffer, in-order DS)
    #pragma unroll
    for (int c = 0; c < 4; ++c)
      #pragma unroll
      for (int i = 0; i < 4; ++i) Ps[w][lg*4 + i][c*16 + l15] = f2bf(p[c][i]);
    short8 pa[2];
    #pragma unroll
    for (int kk = 0; kk < 2; ++kk) pa[kk] = *(const short8*)&Ps[w][l15][kk*32 + lg*8];
    // O += P @ V
    #pragma unroll
    for (int n = 0; n < 4; ++n)
      #pragma unroll
      for (int kk = 0; kk < 2; ++kk) {
        short8 bv = *(const short8*)&VTs[n*16 + l15][kk*32 + lg*8];
        o_[n] = __builtin_amdgcn_mfma_f32_16x16x32_bf16(pa[kk], bv, o_[n], 0, 0, 0);
      }
  }
  #pragma unroll
  for (int i = 0; i < 4; ++i) {
    float inv = 1.f / l_[i];
    int row = qr0 + lg*4 + i;
    #pragma unroll
    for (int n = 0; n < 4; ++n)
      O[(size_t)row * (NH*HD) + h*HD + n*16 + l15] = o_[n][i] * inv;
  }
}

extern "C" void kernel_launch(void* const* d_in, const int* in_sizes, int n_in,
                              void* d_out, int out_size, void* d_ws, size_t ws_size,
                              hipStream_t stream) {
  const float* hs   = (const float*)d_in[0];
  const float* cosb = (const float*)d_in[1];
  const float* sinb = (const float*)d_in[2];
  const float* wq   = (const float*)d_in[3];
  const float* wk   = (const float*)d_in[4];
  const float* wv   = (const float*)d_in[5];
  const float* wo   = (const float*)d_in[6];
  const float* wln1 = (const float*)d_in[7];
  const float* wln2 = (const float*)d_in[8];
  const float* wg   = (const float*)d_in[9];
  const float* wu   = (const float*)d_in[10];
  const float* wd   = (const float*)d_in[11];
  float* out = (float*)d_out;
  char* ws = (char*)d_ws;
  const size_t MB = 1024 * 1024;
  float* xn = (float*)(ws);            // 16 MB; reused for attn output
  float* q  = (float*)(ws + 16*MB);    // 16 MB; reused for y (post-LN2)
  float* k  = (float*)(ws + 32*MB);    //  4 MB
  float* v  = (float*)(ws + 36*MB);    //  4 MB
  float* g  = (float*)(ws + 40*MB);    // 64 MB
  float* attn = xn;
  float* y    = q;

  rmsnorm_kernel<<<S_LEN, 256, 0, stream>>>(hs, wln1, xn);
  gemm_kernel<0><<<dim3(16, 16), 256, 0, stream>>>(xn, wq, q, nullptr, S_LEN, NH*HD, HIDN);
  gemm_kernel<0><<<dim3(16, 4),  256, 0, stream>>>(xn, wk, k, nullptr, S_LEN, NKV*HD, HIDN);
  gemm_kernel<0><<<dim3(16, 4),  256, 0, stream>>>(xn, wv, v, nullptr, S_LEN, NKV*HD, HIDN);
  rope_kernel<<<(S_LEN*(NH+NKV)*32)/256, 256, 0, stream>>>(q, k, cosb, sinb);
  attn_kernel<<<NH*(S_LEN/64), 256, 0, stream>>>(q, k, v, attn);
  gemm_kernel<1><<<dim3(16, 16), 256, 0, stream>>>(attn, wo, out, hs, S_LEN, HIDN, NH*HD);
  rmsnorm_kernel<<<S_LEN, 256, 0, stream>>>(out, wln2, y);
  gemm_kernel<0><<<dim3(16, 64), 256, 0, stream>>>(y, wg, g, nullptr, S_LEN, FFN, HIDN);
  gemm_kernel<2><<<dim3(16, 64), 256, 0, stream>>>(y, wu, g, g, S_LEN, FFN, HIDN);
  gemm_kernel<1><<<dim3(16, 16), 256, 0, stream>>>(g, wd, out, out, S_LEN, HIDN, FFN);
}

// Round 2
// 754.052 us; speedup vs baseline: 1.9849x; 1.9849x over previous
//
#include <hip/hip_runtime.h>
#include <hip/hip_bf16.h>
#include <cstdint>

#define S_LEN 2048
#define HIDN  2048
#define NH    32
#define NKV   8
#define HD    64
#define FFN   8192
#define QKVN  3072   // 2048 q + 512 k + 512 v
#define QKVLD 3072

typedef __attribute__((ext_vector_type(4))) float f32x4;
typedef __attribute__((ext_vector_type(8))) short short8;

__device__ __forceinline__ short f2bf(float f) {
  union { float f; uint32_t u; } v; v.f = f;
  uint32_t r = v.u + 0x7FFFu + ((v.u >> 16) & 1u);
  return (short)(r >> 16);
}
__device__ __forceinline__ float bf2f(short s) {
  union { float f; uint32_t u; } v; v.u = ((uint32_t)(uint16_t)s) << 16;
  return v.f;
}

#define GLOAD_LDS16(gp, lp) \
  __builtin_amdgcn_global_load_lds((const __attribute__((address_space(1))) void*)(gp), \
                                   (__attribute__((address_space(3))) void*)(lp), 16, 0, 0)

// ---------------- transpose-convert: fp32 [K][N] -> bf16 [N][K] ----------------
__global__ __launch_bounds__(256) void convT_kernel(const float* __restrict__ src,
    short* __restrict__ dst, int K, int N) {
  __shared__ float t[64][65];
  const int k0 = blockIdx.x * 64, n0 = blockIdx.y * 64;
  const int tr = threadIdx.x >> 4, tc = (threadIdx.x & 15) * 4;
  #pragma unroll
  for (int i = 0; i < 4; ++i) {
    float4 v = *(const float4*)(src + (size_t)(k0 + tr + i * 16) * N + n0 + tc);
    t[tr + i * 16][tc] = v.x; t[tr + i * 16][tc + 1] = v.y;
    t[tr + i * 16][tc + 2] = v.z; t[tr + i * 16][tc + 3] = v.w;
  }
  __syncthreads();
  const int dr = threadIdx.x >> 2, dc = (threadIdx.x & 3) * 16;
  short8 o0, o1;
  #pragma unroll
  for (int j = 0; j < 8; ++j) { o0[j] = f2bf(t[dc + j][dr]); o1[j] = f2bf(t[dc + 8 + j][dr]); }
  short* dp = dst + (size_t)(n0 + dr) * K + k0 + dc;
  *(short8*)dp = o0;
  *(short8*)(dp + 8) = o1;
}

// ---------------- RMSNorm: fp32 in -> bf16 out ----------------
__global__ __launch_bounds__(256) void rmsnorm_kernel(const float* __restrict__ X,
    const float* __restrict__ W, short* __restrict__ Y) {
  int row = blockIdx.x;
  const float4* x4 = (const float4*)(X + (size_t)row * HIDN);
  const float4* w4 = (const float4*)W;
  float4 v0 = x4[2 * threadIdx.x];
  float4 v1 = x4[2 * threadIdx.x + 1];
  float ss = v0.x*v0.x + v0.y*v0.y + v0.z*v0.z + v0.w*v0.w
           + v1.x*v1.x + v1.y*v1.y + v1.z*v1.z + v1.w*v1.w;
  #pragma unroll
  for (int off = 32; off > 0; off >>= 1) ss += __shfl_xor(ss, off, 64);
  __shared__ float red[4];
  if ((threadIdx.x & 63) == 0) red[threadIdx.x >> 6] = ss;
  __syncthreads();
  ss = red[0] + red[1] + red[2] + red[3];
  float rs = rsqrtf(ss * (1.0f / HIDN) + 1e-5f);
  float4 w0 = w4[2 * threadIdx.x], w1 = w4[2 * threadIdx.x + 1];
  short8 o;
  o[0] = f2bf(v0.x * rs * w0.x); o[1] = f2bf(v0.y * rs * w0.y);
  o[2] = f2bf(v0.z * rs * w0.z); o[3] = f2bf(v0.w * rs * w0.w);
  o[4] = f2bf(v1.x * rs * w1.x); o[5] = f2bf(v1.y * rs * w1.y);
  o[6] = f2bf(v1.z * rs * w1.z); o[7] = f2bf(v1.w * rs * w1.w);
  *(short8*)(Y + (size_t)row * HIDN + threadIdx.x * 8) = o;
}

// ---------------- GEMM: C[M][N] = A[M][Kfull] @ BT[N][Kfull]^T (bf16 MFMA) ----
// EPI 0: C bf16 = acc
// EPI 1: C f32  = acc + Xf32
// EPI 2: C bf16 = silu(Xbf16) * acc
// EPI 3: C f32 partial (split-K): C[z*M*N + idx] = acc
template<int EPI>
__global__ __launch_bounds__(256) void gemm_bt(const short* __restrict__ A,
    const short* __restrict__ BT, void* __restrict__ Cp, const void* __restrict__ Xp,
    int M, int N, int Kfull, int KC) {
  __shared__ __align__(16) short As[128 * 32];
  __shared__ __align__(16) short Bs[128 * 32];
  const int tid = threadIdx.x, lane = tid & 63, w = tid >> 6;
  const int wm = (w >> 1) * 64, wn = (w & 1) * 64;
  const int l15 = lane & 15, lg = lane >> 4;
  const int brow = blockIdx.x * 128, bcol = blockIdx.y * 128;
  const int z = blockIdx.z;
  const size_t kbase = (size_t)z * KC;
  const int sr = lane >> 2;            // row within 16-row chunk
  const int sc = (lane & 3) * 8;       // col element within 32
  f32x4 acc[4][4] = {};

  for (int k0 = 0; k0 < KC; k0 += 32) {
    #pragma unroll
    for (int i = 0; i < 2; ++i) {
      const int c = w * 2 + i;
      const short* ga = A + (size_t)(brow + c * 16 + sr) * Kfull + kbase + k0 + sc;
      GLOAD_LDS16(ga, As + c * 512);
      const short* gb = BT + (size_t)(bcol + c * 16 + sr) * Kfull + kbase + k0 + sc;
      GLOAD_LDS16(gb, Bs + c * 512);
    }
    __syncthreads();   // drains vmcnt; LDS tiles ready
    short8 af[4], bf[4];
    #pragma unroll
    for (int m = 0; m < 4; ++m) af[m] = *(const short8*)&As[(wm + m * 16 + l15) * 32 + lg * 8];
    #pragma unroll
    for (int n = 0; n < 4; ++n) bf[n] = *(const short8*)&Bs[(wn + n * 16 + l15) * 32 + lg * 8];
    #pragma unroll
    for (int m = 0; m < 4; ++m)
      #pragma unroll
      for (int n = 0; n < 4; ++n)
        acc[m][n] = __builtin_amdgcn_mfma_f32_16x16x32_bf16(af[m], bf[n], acc[m][n], 0, 0, 0);
    __syncthreads();   // all reads done before next-tile overwrite
  }

  const int r0 = brow + wm + lg * 4;
  const int c0 = bcol + wn + l15;
  #pragma unroll
  for (int m = 0; m < 4; ++m)
    #pragma unroll
    for (int n = 0; n < 4; ++n)
      #pragma unroll
      for (int i = 0; i < 4; ++i) {
        const size_t idx = (size_t)(r0 + m * 16 + i) * N + (c0 + n * 16);
        float v = acc[m][n][i];
        if (EPI == 0) ((short*)Cp)[idx] = f2bf(v);
        if (EPI == 1) ((float*)Cp)[idx] = v + ((const float*)Xp)[idx];
        if (EPI == 2) {
          float gf = bf2f(((const short*)Xp)[idx]);
          ((short*)Cp)[idx] = f2bf(gf / (1.f + __expf(-gf)) * v);
        }
        if (EPI == 3) ((float*)Cp)[(size_t)z * M * N + idx] = v;
      }
}

// ---------------- RoPE (in-place on bf16 qkv, q + k heads) ----------------
__global__ __launch_bounds__(256) void rope_kernel(short* __restrict__ qkv,
    const float* __restrict__ cosb, const float* __restrict__ sinb) {
  int idx = blockIdx.x * 256 + threadIdx.x;
  int d = idx & 31;
  int hh = (idx >> 5) % (NH + NKV);
  int s = idx / (32 * (NH + NKV));
  int col = (hh < NH) ? hh * HD : HIDN + (hh - NH) * HD;
  short* base = qkv + (size_t)s * QKVLD + col;
  float c  = cosb[s * HD + d];
  float sn = sinb[s * HD + d];
  float x1 = bf2f(base[d]), x2 = bf2f(base[d + 32]);
  base[d]      = f2bf(x1 * c - x2 * sn);
  base[d + 32] = f2bf(x2 * c + x1 * sn);
}

// ---------------- Flash attention (causal, GQA), bf16 in/out ----------------
__global__ __launch_bounds__(256) void attn_kernel(const short* __restrict__ QKV,
    short* __restrict__ O) {
  __shared__ __align__(16) short Ks[64][72];
  __shared__ __align__(16) short VTs[64][72];
  __shared__ __align__(16) short Ps[4][16][72];
  const int h  = blockIdx.x >> 5;
  const int qt = blockIdx.x & 31;
  const int kvh = h >> 2;
  const int tid = threadIdx.x, lane = tid & 63, w = tid >> 6;
  const int l15 = lane & 15, lg = lane >> 4;
  const int qr0 = qt * 64 + w * 16;
  const int kcol = HIDN + kvh * HD;        // K base col in qkv row
  const int vcol = HIDN + NKV * HD + kvh * HD;
  // Q fragments, scale 1/8 folded (exact power of two)
  short8 aq[2];
  #pragma unroll
  for (int kk = 0; kk < 2; ++kk) {
    short8 qv = *(const short8*)(QKV + (size_t)(qr0 + l15) * QKVLD + h * HD + kk * 32 + lg * 8);
    #pragma unroll
    for (int e = 0; e < 8; ++e) aq[kk][e] = f2bf(bf2f(qv[e]) * 0.125f);
  }
  float m_[4] = {-3e38f, -3e38f, -3e38f, -3e38f};
  float l_[4] = {0.f, 0.f, 0.f, 0.f};
  f32x4 o_[4] = {};
  const int srow = tid >> 3, sc8 = (tid & 7) * 8;

  for (int t = 0; t <= qt; ++t) {
    const int kb = t * 64;
    __syncthreads();
    #pragma unroll
    for (int i = 0; i < 2; ++i) {
      const int r = i * 32 + srow;
      short8 kv = *(const short8*)(QKV + (size_t)(kb + r) * QKVLD + kcol + sc8);
      *(short8*)&Ks[r][sc8] = kv;
      short8 vv = *(const short8*)(QKV + (size_t)(kb + r) * QKVLD + vcol + sc8);
      #pragma unroll
      for (int j = 0; j < 8; ++j) VTs[sc8 + j][r] = vv[j];
    }
    __syncthreads();
    f32x4 s[4] = {};
    #pragma unroll
    for (int c = 0; c < 4; ++c)
      #pragma unroll
      for (int kk = 0; kk < 2; ++kk) {
        short8 bk = *(const short8*)&Ks[c * 16 + l15][kk * 32 + lg * 8];
        s[c] = __builtin_amdgcn_mfma_f32_16x16x32_bf16(aq[kk], bk, s[c], 0, 0, 0);
      }
    if (t == qt) {
      #pragma unroll
      for (int c = 0; c < 4; ++c)
        #pragma unroll
        for (int i = 0; i < 4; ++i) {
          int rq = qr0 + lg * 4 + i;
          int ck = kb + c * 16 + l15;
          if (ck > rq) s[c][i] = -1e30f;
        }
    }
    float pm[4], mn[4], al[4];
    #pragma unroll
    for (int i = 0; i < 4; ++i) {
      float vmx = fmaxf(fmaxf(s[0][i], s[1][i]), fmaxf(s[2][i], s[3][i]));
      #pragma unroll
      for (int off = 1; off < 16; off <<= 1) vmx = fmaxf(vmx, __shfl_xor(vmx, off, 16));
      pm[i] = vmx;
      mn[i] = fmaxf(m_[i], pm[i]);
      al[i] = __expf(m_[i] - mn[i]);
    }
    float p[4][4];
    float rsum[4] = {0.f, 0.f, 0.f, 0.f};
    #pragma unroll
    for (int c = 0; c < 4; ++c)
      #pragma unroll
      for (int i = 0; i < 4; ++i) { p[c][i] = __expf(s[c][i] - mn[i]); rsum[i] += p[c][i]; }
    #pragma unroll
    for (int i = 0; i < 4; ++i) {
      float vs = rsum[i];
      #pragma unroll
      for (int off = 1; off < 16; off <<= 1) vs += __shfl_xor(vs, off, 16);
      l_[i] = l_[i] * al[i] + vs;
      m_[i] = mn[i];
    }
    #pragma unroll
    for (int n = 0; n < 4; ++n)
      #pragma unroll
      for (int i = 0; i < 4; ++i) o_[n][i] *= al[i];
    #pragma unroll
    for (int c = 0; c < 4; ++c)
      #pragma unroll
      for (int i = 0; i < 4; ++i) Ps[w][lg * 4 + i][c * 16 + l15] = f2bf(p[c][i]);
    short8 pa[2];
    #pragma unroll
    for (int kk = 0; kk < 2; ++kk) pa[kk] = *(const short8*)&Ps[w][l15][kk * 32 + lg * 8];
    #pragma unroll
    for (int n = 0; n < 4; ++n)
      #pragma unroll
      for (int kk = 0; kk < 2; ++kk) {
        short8 bv = *(const short8*)&VTs[n * 16 + l15][kk * 32 + lg * 8];
        o_[n] = __builtin_amdgcn_mfma_f32_16x16x32_bf16(pa[kk], bv, o_[n], 0, 0, 0);
      }
  }
  #pragma unroll
  for (int i = 0; i < 4; ++i) {
    float inv = 1.f / l_[i];
    int row = qr0 + lg * 4 + i;
    #pragma unroll
    for (int n = 0; n < 4; ++n)
      O[(size_t)row * HIDN + h * HD + n * 16 + l15] = f2bf(o_[n][i] * inv);
  }
}

// ---------------- out += P0 + P1 (split-K reduce) ----------------
__global__ __launch_bounds__(256) void reduce_kernel(float* __restrict__ out,
    const float* __restrict__ P) {
  const size_t n = (size_t)S_LEN * HIDN;
  size_t i = ((size_t)blockIdx.x * 256 + threadIdx.x) * 4;
  float4 o = *(float4*)(out + i);
  float4 a = *(const float4*)(P + i);
  float4 b = *(const float4*)(P + n + i);
  o.x += a.x + b.x; o.y += a.y + b.y; o.z += a.z + b.z; o.w += a.w + b.w;
  *(float4*)(out + i) = o;
}

extern "C" void kernel_launch(void* const* d_in, const int* in_sizes, int n_in,
                              void* d_out, int out_size, void* d_ws, size_t ws_size,
                              hipStream_t stream) {
  const float* hs   = (const float*)d_in[0];
  const float* cosb = (const float*)d_in[1];
  const float* sinb = (const float*)d_in[2];
  const float* wq   = (const float*)d_in[3];
  const float* wk   = (const float*)d_in[4];
  const float* wv   = (const float*)d_in[5];
  const float* wo   = (const float*)d_in[6];
  const float* wln1 = (const float*)d_in[7];
  const float* wln2 = (const float*)d_in[8];
  const float* wg   = (const float*)d_in[9];
  const float* wu   = (const float*)d_in[10];
  const float* wd   = (const float*)d_in[11];
  float* out = (float*)d_out;
  char* ws = (char*)d_ws;
  const size_t MB = 1024 * 1024;
  short* xn    = (short*)(ws);             //  8 MB bf16 [2048][2048]
  short* y     = (short*)(ws + 8 * MB);    //  8 MB
  short* attnO = (short*)(ws + 16 * MB);   //  8 MB
  short* qkv   = (short*)(ws + 24 * MB);   // 12.6 MB bf16 [2048][3072]
  short* g     = (short*)(ws + 37 * MB);   // 32 MB bf16 [2048][8192] (gate, then h in-place)
  short* Wbuf  = (short*)(ws + 69 * MB);   // 32 MB time-shared transposed weights
  float* P     = (float*)(ws);             // 32 MB split-K partials (aliases dead xn/y/attnO/qkv)

  // weights for QKV (packed rows: q 0..2047, k 2048..2559, v 2560..3071)
  convT_kernel<<<dim3(32, 32), 256, 0, stream>>>(wq, Wbuf, HIDN, NH * HD);
  convT_kernel<<<dim3(32, 8),  256, 0, stream>>>(wk, Wbuf + (size_t)2048 * HIDN, HIDN, NKV * HD);
  convT_kernel<<<dim3(32, 8),  256, 0, stream>>>(wv, Wbuf + (size_t)2560 * HIDN, HIDN, NKV * HD);
  rmsnorm_kernel<<<S_LEN, 256, 0, stream>>>(hs, wln1, xn);
  gemm_bt<0><<<dim3(16, 24), 256, 0, stream>>>(xn, Wbuf, qkv, nullptr, S_LEN, QKVN, HIDN, HIDN);
  // WO weight convert (safe: qkv GEMM already ordered before on stream)
  convT_kernel<<<dim3(32, 32), 256, 0, stream>>>(wo, Wbuf, NH * HD, HIDN);
  rope_kernel<<<(S_LEN * (NH + NKV) * 32) / 256, 256, 0, stream>>>(qkv, cosb, sinb);
  attn_kernel<<<NH * (S_LEN / 64), 256, 0, stream>>>(qkv, attnO);
  gemm_bt<1><<<dim3(16, 16), 256, 0, stream>>>(attnO, Wbuf, out, hs, S_LEN, HIDN, NH * HD, NH * HD);
  rmsnorm_kernel<<<S_LEN, 256, 0, stream>>>(out, wln2, y);
  convT_kernel<<<dim3(32, 128), 256, 0, stream>>>(wg, Wbuf, HIDN, FFN);
  gemm_bt<0><<<dim3(16, 64), 256, 0, stream>>>(y, Wbuf, g, nullptr, S_LEN, FFN, HIDN, HIDN);
  convT_kernel<<<dim3(32, 128), 256, 0, stream>>>(wu, Wbuf, HIDN, FFN);
  gemm_bt<2><<<dim3(16, 64), 256, 0, stream>>>(y, Wbuf, g, g, S_LEN, FFN, HIDN, HIDN);
  convT_kernel<<<dim3(128, 32), 256, 0, stream>>>(wd, Wbuf, FFN, HIDN);
  gemm_bt<3><<<dim3(16, 16, 2), 256, 0, stream>>>(g, Wbuf, P, nullptr, S_LEN, HIDN, FFN, FFN / 2);
  reduce_kernel<<<(S_LEN * HIDN) / 1024, 256, 0, stream>>>(out, P);
}

// Round 4
// 513.743 us; speedup vs baseline: 2.9133x; 1.4678x over previous
//
#include <hip/hip_runtime.h>
#include <hip/hip_bf16.h>
#include <cstdint>

#define S_LEN 2048
#define HIDN  2048
#define NH    32
#define NKV   8
#define HD    64
#define FFN   8192
#define QKVN  3072   // 2048 q + 512 k + 512 v
#define QKVLD 3072

typedef __attribute__((ext_vector_type(4)))  float f32x4;
typedef __attribute__((ext_vector_type(16))) float f32x16;
typedef __attribute__((ext_vector_type(8)))  short short8;
typedef __attribute__((ext_vector_type(4)))  short s16x4;

__device__ __forceinline__ short f2bf(float f) {
  union { float f; uint32_t u; } v; v.f = f;
  uint32_t r = v.u + 0x7FFFu + ((v.u >> 16) & 1u);
  return (short)(r >> 16);
}
__device__ __forceinline__ float bf2f(short s) {
  union { float f; uint32_t u; } v; v.u = ((uint32_t)(uint16_t)s) << 16;
  return v.f;
}
__device__ __forceinline__ unsigned packbf2(float lo, float hi) {
  return (unsigned)(uint16_t)f2bf(lo) | ((unsigned)(uint16_t)f2bf(hi) << 16);
}

#define GLOAD_LDS16(gp, lp) \
  __builtin_amdgcn_global_load_lds((const __attribute__((address_space(1))) void*)(gp), \
                                   (__attribute__((address_space(3))) void*)(lp), 16, 0, 0)

// ---------------- transpose-convert: fp32 [K][N] -> bf16 [N][K] ----------------
__global__ __launch_bounds__(256) void convT_kernel(const float* __restrict__ src,
    short* __restrict__ dst, int K, int N) {
  __shared__ float t[64][65];
  const int k0 = blockIdx.x * 64, n0 = blockIdx.y * 64;
  const int tr = threadIdx.x >> 4, tc = (threadIdx.x & 15) * 4;
  #pragma unroll
  for (int i = 0; i < 4; ++i) {
    float4 v = *(const float4*)(src + (size_t)(k0 + tr + i * 16) * N + n0 + tc);
    t[tr + i * 16][tc] = v.x; t[tr + i * 16][tc + 1] = v.y;
    t[tr + i * 16][tc + 2] = v.z; t[tr + i * 16][tc + 3] = v.w;
  }
  __syncthreads();
  const int dr = threadIdx.x >> 2, dc = (threadIdx.x & 3) * 16;
  short8 o0, o1;
  #pragma unroll
  for (int j = 0; j < 8; ++j) { o0[j] = f2bf(t[dc + j][dr]); o1[j] = f2bf(t[dc + 8 + j][dr]); }
  short* dp = dst + (size_t)(n0 + dr) * K + k0 + dc;
  *(short8*)dp = o0;
  *(short8*)(dp + 8) = o1;
}

// ---------------- RMSNorm: fp32 in -> bf16 out ----------------
__global__ __launch_bounds__(256) void rmsnorm_kernel(const float* __restrict__ X,
    const float* __restrict__ W, short* __restrict__ Y) {
  int row = blockIdx.x;
  const float4* x4 = (const float4*)(X + (size_t)row * HIDN);
  const float4* w4 = (const float4*)W;
  float4 v0 = x4[2 * threadIdx.x];
  float4 v1 = x4[2 * threadIdx.x + 1];
  float ss = v0.x*v0.x + v0.y*v0.y + v0.z*v0.z + v0.w*v0.w
           + v1.x*v1.x + v1.y*v1.y + v1.z*v1.z + v1.w*v1.w;
  #pragma unroll
  for (int off = 32; off > 0; off >>= 1) ss += __shfl_xor(ss, off, 64);
  __shared__ float red[4];
  if ((threadIdx.x & 63) == 0) red[threadIdx.x >> 6] = ss;
  __syncthreads();
  ss = red[0] + red[1] + red[2] + red[3];
  float rs = rsqrtf(ss * (1.0f / HIDN) + 1e-5f);
  float4 w0 = w4[2 * threadIdx.x], w1 = w4[2 * threadIdx.x + 1];
  short8 o;
  o[0] = f2bf(v0.x * rs * w0.x); o[1] = f2bf(v0.y * rs * w0.y);
  o[2] = f2bf(v0.z * rs * w0.z); o[3] = f2bf(v0.w * rs * w0.w);
  o[4] = f2bf(v1.x * rs * w1.x); o[5] = f2bf(v1.y * rs * w1.y);
  o[6] = f2bf(v1.z * rs * w1.z); o[7] = f2bf(v1.w * rs * w1.w);
  *(short8*)(Y + (size_t)row * HIDN + threadIdx.x * 8) = o;
}

// ---------------- GEMM: C[M][N] = A[M][Kfull] @ BT[N][Kfull]^T (bf16 MFMA) ----
// BK=64, linear LDS + pre-swizzled global source (blk ^ row&7), gload_lds w16.
// EPI 0: C bf16 = acc | 1: C f32 = acc + Xf32 | 2: C bf16 = silu(Xbf16)*acc
// EPI 3: C f32 partial (split-K over blockIdx.y)
template<int EPI>
__global__ __launch_bounds__(256) void gemm_bt(const short* __restrict__ A,
    const short* __restrict__ BT, void* __restrict__ Cp, const void* __restrict__ Xp,
    int M, int N, int Kfull, int KC, int gx) {
  __shared__ __align__(16) short As[128 * 64];
  __shared__ __align__(16) short Bs[128 * 64];
  const int tid = threadIdx.x, lane = tid & 63, w = tid >> 6;
  const int wm = (w >> 1) * 64, wn = (w & 1) * 64;
  const int l15 = lane & 15, lg = lane >> 4;
  // bijective XCD remap (nwg % 8 == 0 for all our launches)
  const int nwg = gridDim.x;
  const int qq = nwg >> 3, xcd = blockIdx.x & 7, off = blockIdx.x >> 3;
  const int wg = xcd * qq + off;
  const int brow = (wg % gx) * 128, bcol = (wg / gx) * 128;
  const size_t kbase = (size_t)blockIdx.y * KC;
  const int srow8 = lane >> 3;          // row offset within 8-row chunk
  const int gblk  = (lane & 7) ^ (srow8 & 7);  // pre-swizzled global 16B-block
  f32x4 acc[4][4] = {};

  for (int k0 = 0; k0 < KC; k0 += 64) {
    #pragma unroll
    for (int j = 0; j < 4; ++j) {
      const int rbase = w * 32 + j * 8;
      const int row = rbase + srow8;
      const short* ga = A + (size_t)(brow + row) * Kfull + kbase + k0 + gblk * 8;
      GLOAD_LDS16(ga, As + rbase * 64);
      const short* gb = BT + (size_t)(bcol + row) * Kfull + kbase + k0 + gblk * 8;
      GLOAD_LDS16(gb, Bs + rbase * 64);
    }
    __syncthreads();   // drains vmcnt; tiles ready
    #pragma unroll
    for (int kk = 0; kk < 2; ++kk) {
      short8 af[4], bf[4];
      #pragma unroll
      for (int m = 0; m < 4; ++m) {
        const int row = wm + m * 16 + l15;
        af[m] = *(const short8*)&As[row * 64 + (((kk * 4 + lg) ^ (l15 & 7)) * 8)];
      }
      #pragma unroll
      for (int n = 0; n < 4; ++n) {
        const int row = wn + n * 16 + l15;
        bf[n] = *(const short8*)&Bs[row * 64 + (((kk * 4 + lg) ^ (l15 & 7)) * 8)];
      }
      #pragma unroll
      for (int m = 0; m < 4; ++m)
        #pragma unroll
        for (int n = 0; n < 4; ++n)
          acc[m][n] = __builtin_amdgcn_mfma_f32_16x16x32_bf16(af[m], bf[n], acc[m][n], 0, 0, 0);
    }
    __syncthreads();   // reads done before next DMA overwrite
  }

  const int r0 = brow + wm + lg * 4;
  const int c0 = bcol + wn + l15;
  #pragma unroll
  for (int m = 0; m < 4; ++m)
    #pragma unroll
    for (int n = 0; n < 4; ++n)
      #pragma unroll
      for (int i = 0; i < 4; ++i) {
        const size_t idx = (size_t)(r0 + m * 16 + i) * N + (c0 + n * 16);
        float v = acc[m][n][i];
        if (EPI == 0) ((short*)Cp)[idx] = f2bf(v);
        if (EPI == 1) ((float*)Cp)[idx] = v + ((const float*)Xp)[idx];
        if (EPI == 2) {
          float gf = bf2f(((const short*)Xp)[idx]);
          ((short*)Cp)[idx] = f2bf(gf / (1.f + __expf(-gf)) * v);
        }
        if (EPI == 3) ((float*)Cp)[(size_t)blockIdx.y * M * N + idx] = v;
      }
}

// ---------------- RoPE (in-place on bf16 qkv, q + k heads) ----------------
__global__ __launch_bounds__(256) void rope_kernel(short* __restrict__ qkv,
    const float* __restrict__ cosb, const float* __restrict__ sinb) {
  int idx = blockIdx.x * 256 + threadIdx.x;
  int d = idx & 31;
  int hh = (idx >> 5) % (NH + NKV);
  int s = idx / (32 * (NH + NKV));
  int col = (hh < NH) ? hh * HD : HIDN + (hh - NH) * HD;
  short* base = qkv + (size_t)s * QKVLD + col;
  float c  = cosb[s * HD + d];
  float sn = sinb[s * HD + d];
  float x1 = bf2f(base[d]), x2 = bf2f(base[d + 32]);
  base[d]      = f2bf(x1 * c - x2 * sn);
  base[d + 32] = f2bf(x2 * c + x1 * sn);
}

// ---------------- Flash attention: swapped-operand 32x32x16 structure --------
// Per block: 4 waves x 32 q-rows = 128 q. KV tiles of 64. S^T = mfma(K, Q^T):
// lane owns q = lane&31; softmax in-register + one shfl_xor(32).
// PV: O^T = mfma(V^T, P^T) keeps q lane-local.
__global__ __launch_bounds__(256) void attn_kernel(const short* __restrict__ QKV,
    short* __restrict__ O) {
  __shared__ __align__(16) short Ks[64][72];
  __shared__ __align__(16) short VTs[64][72];
  const int bid = blockIdx.x;
  const int half = bid >> 8, idx = bid & 255;
  const int h = idx & 31;
  int qt = idx >> 5;                 // 0..7
  qt = half ? (15 - qt) : qt;        // balance: paired blocks sum to const work
  const int kvh = h >> 2;
  const int tid = threadIdx.x, lane = tid & 63, w = tid >> 6;
  const int l31 = lane & 31, hi = lane >> 5;
  const int qb = qt * 128 + w * 32;
  const int kcol = HIDN + kvh * HD;
  const int vcol = HIDN + NKV * HD + kvh * HD;

  // Q fragments (B-operand: lane holds q=l31, d = dk*16 + hi*8 + e), scale 1/8
  short8 Qr[4];
  {
    const short* qp = QKV + (size_t)(qb + l31) * QKVLD + h * HD;
    #pragma unroll
    for (int dk = 0; dk < 4; ++dk) {
      short8 qv = *(const short8*)(qp + dk * 16 + hi * 8);
      #pragma unroll
      for (int e = 0; e < 8; ++e) Qr[dk][e] = f2bf(bf2f(qv[e]) * 0.125f);
    }
  }
  float m_ = -3e38f, l_ = 0.f;
  f32x16 o0 = {}, o1 = {};
  const int nt = 2 * qt + 2;
  const int krow = tid >> 2, kcb = (tid & 3) * 16;   // K staging map
  const int vk = tid & 31, vdb = (tid >> 5) * 8;     // V staging map

  for (int t = 0; t < nt; ++t) {
    const int kb = t * 64;
    __syncthreads();
    { // stage K row-major [64][72]
      const short* gk = QKV + (size_t)(kb + krow) * QKVLD + kcol + kcb;
      short8 a = *(const short8*)gk;
      short8 b = *(const short8*)(gk + 8);
      *(short8*)&Ks[krow][kcb] = a;
      *(short8*)&Ks[krow][kcb + 8] = b;
    }
    #pragma unroll
    for (int i = 0; i < 2; ++i) { // stage V^T [d][k]
      const int k = i * 32 + vk;
      short8 v = *(const short8*)(QKV + (size_t)(kb + k) * QKVLD + vcol + vdb);
      #pragma unroll
      for (int j = 0; j < 8; ++j) VTs[vdb + j][k] = v[j];
    }
    __syncthreads();
    if (kb < qb + 32) {          // not fully masked for this wave
      // S^T: rows k, cols q. lane: q = l31; k = kt*32 + (r&3)+8*(r>>2)+4*hi
      f32x16 s[2] = {};
      #pragma unroll
      for (int kt = 0; kt < 2; ++kt)
        #pragma unroll
        for (int dk = 0; dk < 4; ++dk) {
          short8 kf = *(const short8*)&Ks[kt * 32 + l31][dk * 16 + hi * 8];
          s[kt] = __builtin_amdgcn_mfma_f32_32x32x16_bf16(kf, Qr[dk], s[kt], 0, 0, 0);
        }
      if (kb + 63 > qb) {        // diagonal: per-element causal mask
        const int qg = qb + l31;
        #pragma unroll
        for (int kt = 0; kt < 2; ++kt)
          #pragma unroll
          for (int r = 0; r < 16; ++r) {
            const int kg = kb + kt * 32 + (r & 3) + 8 * (r >> 2) + 4 * hi;
            if (kg > qg) s[kt][r] = -1e30f;
          }
      }
      // online softmax (q lane-local; halves hold complementary k)
      float pm = s[0][0];
      #pragma unroll
      for (int r = 1; r < 16; ++r) pm = fmaxf(pm, s[0][r]);
      #pragma unroll
      for (int r = 0; r < 16; ++r) pm = fmaxf(pm, s[1][r]);
      pm = fmaxf(pm, __shfl_xor(pm, 32));
      const float mn = fmaxf(m_, pm);
      const float al = __expf(m_ - mn);
      float rsum = 0.f;
      #pragma unroll
      for (int kt = 0; kt < 2; ++kt)
        #pragma unroll
        for (int r = 0; r < 16; ++r) { s[kt][r] = __expf(s[kt][r] - mn); rsum += s[kt][r]; }
      rsum += __shfl_xor(rsum, 32);
      l_ = l_ * al + rsum;
      m_ = mn;
      o0 *= al; o1 *= al;
      // pack P -> bf16 words; swap halves to build B-fragments (P^T)
      unsigned wd[2][8], rw[2][8];
      #pragma unroll
      for (int kt = 0; kt < 2; ++kt)
        #pragma unroll
        for (int i = 0; i < 8; ++i) {
          wd[kt][i] = packbf2(s[kt][2 * i], s[kt][2 * i + 1]);
          rw[kt][i] = (unsigned)__shfl_xor((int)wd[kt][i], 32);
        }
      #pragma unroll
      for (int kt = 0; kt < 2; ++kt) {
        union { unsigned u[4]; short8 s8; } pf0, pf1;
        if (hi) {
          pf0.u[0] = rw[kt][2]; pf0.u[1] = rw[kt][3]; pf0.u[2] = wd[kt][2]; pf0.u[3] = wd[kt][3];
          pf1.u[0] = rw[kt][6]; pf1.u[1] = rw[kt][7]; pf1.u[2] = wd[kt][6]; pf1.u[3] = wd[kt][7];
        } else {
          pf0.u[0] = wd[kt][0]; pf0.u[1] = wd[kt][1]; pf0.u[2] = rw[kt][0]; pf0.u[3] = rw[kt][1];
          pf1.u[0] = wd[kt][4]; pf1.u[1] = wd[kt][5]; pf1.u[2] = rw[kt][4]; pf1.u[3] = rw[kt][5];
        }
        // PV: O^T += V^T . P^T  (A = V^T rows d, B = P^T cols q)
        #pragma unroll
        for (int ks = 0; ks < 2; ++ks) {
          const short8 pB = ks ? pf1.s8 : pf0.s8;
          short8 va = *(const short8*)&VTs[l31][kt * 32 + ks * 16 + hi * 8];
          o0 = __builtin_amdgcn_mfma_f32_32x32x16_bf16(va, pB, o0, 0, 0, 0);
          short8 vb = *(const short8*)&VTs[32 + l31][kt * 32 + ks * 16 + hi * 8];
          o1 = __builtin_amdgcn_mfma_f32_32x32x16_bf16(vb, pB, o1, 0, 0, 0);
        }
      }
    }
  }
  // write O: lane q = l31; d = dt*32 + g*8 + hi*4 + 0..3 (regs 4g..4g+3)
  const float inv = 1.f / l_;
  short* op = O + (size_t)(qb + l31) * HIDN + h * HD;
  #pragma unroll
  for (int dt = 0; dt < 2; ++dt) {
    const f32x16& o = dt ? o1 : o0;
    #pragma unroll
    for (int g = 0; g < 4; ++g) {
      s16x4 st;
      st[0] = f2bf(o[g * 4 + 0] * inv);
      st[1] = f2bf(o[g * 4 + 1] * inv);
      st[2] = f2bf(o[g * 4 + 2] * inv);
      st[3] = f2bf(o[g * 4 + 3] * inv);
      *(s16x4*)(op + dt * 32 + g * 8 + hi * 4) = st;
    }
  }
}

// ---------------- out += P0 + P1 (split-K reduce) ----------------
__global__ __launch_bounds__(256) void reduce_kernel(float* __restrict__ out,
    const float* __restrict__ P) {
  const size_t n = (size_t)S_LEN * HIDN;
  size_t i = ((size_t)blockIdx.x * 256 + threadIdx.x) * 4;
  float4 o = *(float4*)(out + i);
  float4 a = *(const float4*)(P + i);
  float4 b = *(const float4*)(P + n + i);
  o.x += a.x + b.x; o.y += a.y + b.y; o.z += a.z + b.z; o.w += a.w + b.w;
  *(float4*)(out + i) = o;
}

extern "C" void kernel_launch(void* const* d_in, const int* in_sizes, int n_in,
                              void* d_out, int out_size, void* d_ws, size_t ws_size,
                              hipStream_t stream) {
  const float* hs   = (const float*)d_in[0];
  const float* cosb = (const float*)d_in[1];
  const float* sinb = (const float*)d_in[2];
  const float* wq   = (const float*)d_in[3];
  const float* wk   = (const float*)d_in[4];
  const float* wv   = (const float*)d_in[5];
  const float* wo   = (const float*)d_in[6];
  const float* wln1 = (const float*)d_in[7];
  const float* wln2 = (const float*)d_in[8];
  const float* wg   = (const float*)d_in[9];
  const float* wu   = (const float*)d_in[10];
  const float* wd   = (const float*)d_in[11];
  float* out = (float*)d_out;
  char* ws = (char*)d_ws;
  const size_t MB = 1024 * 1024;
  short* xn    = (short*)(ws);             //  8 MB bf16 [2048][2048]
  short* y     = (short*)(ws + 8 * MB);    //  8 MB
  short* attnO = (short*)(ws + 16 * MB);   //  8 MB
  short* qkv   = (short*)(ws + 24 * MB);   // 12.6 MB bf16 [2048][3072]
  short* g     = (short*)(ws + 37 * MB);   // 32 MB bf16 [2048][8192]
  short* Wbuf  = (short*)(ws + 69 * MB);   // 32 MB time-shared transposed weights
  float* P     = (float*)(ws);             // 32 MB split-K partials (aliases dead bufs)

  convT_kernel<<<dim3(32, 32), 256, 0, stream>>>(wq, Wbuf, HIDN, NH * HD);
  convT_kernel<<<dim3(32, 8),  256, 0, stream>>>(wk, Wbuf + (size_t)2048 * HIDN, HIDN, NKV * HD);
  convT_kernel<<<dim3(32, 8),  256, 0, stream>>>(wv, Wbuf + (size_t)2560 * HIDN, HIDN, NKV * HD);
  rmsnorm_kernel<<<S_LEN, 256, 0, stream>>>(hs, wln1, xn);
  gemm_bt<0><<<dim3(16 * 24, 1), 256, 0, stream>>>(xn, Wbuf, qkv, nullptr, S_LEN, QKVN, HIDN, HIDN, 16);
  convT_kernel<<<dim3(32, 32), 256, 0, stream>>>(wo, Wbuf, NH * HD, HIDN);
  rope_kernel<<<(S_LEN * (NH + NKV) * 32) / 256, 256, 0, stream>>>(qkv, cosb, sinb);
  attn_kernel<<<NH * (S_LEN / 128), 256, 0, stream>>>(qkv, attnO);
  gemm_bt<1><<<dim3(16 * 16, 1), 256, 0, stream>>>(attnO, Wbuf, out, hs, S_LEN, HIDN, NH * HD, NH * HD, 16);
  rmsnorm_kernel<<<S_LEN, 256, 0, stream>>>(out, wln2, y);
  convT_kernel<<<dim3(32, 128), 256, 0, stream>>>(wg, Wbuf, HIDN, FFN);
  gemm_bt<0><<<dim3(16 * 64, 1), 256, 0, stream>>>(y, Wbuf, g, nullptr, S_LEN, FFN, HIDN, HIDN, 16);
  convT_kernel<<<dim3(32, 128), 256, 0, stream>>>(wu, Wbuf, HIDN, FFN);
  gemm_bt<2><<<dim3(16 * 64, 1), 256, 0, stream>>>(y, Wbuf, g, g, S_LEN, FFN, HIDN, HIDN, 16);
  convT_kernel<<<dim3(128, 32), 256, 0, stream>>>(wd, Wbuf, FFN, HIDN);
  gemm_bt<3><<<dim3(16 * 16, 2), 256, 0, stream>>>(g, Wbuf, P, nullptr, S_LEN, HIDN, FFN, FFN / 2, 16);
  reduce_kernel<<<(S_LEN * HIDN) / 1024, 256, 0, stream>>>(out, P);
}

// Round 5
// 505.312 us; speedup vs baseline: 2.9619x; 1.0167x over previous
//
#include <hip/hip_runtime.h>
#include <hip/hip_bf16.h>
#include <cstdint>

#define S_LEN 2048
#define HIDN  2048
#define NH    32
#define NKV   8
#define HD    64
#define FFN   8192
#define QKVN  3072   // 2048 q + 512 k + 512 v
#define QKVLD 3072

typedef __attribute__((ext_vector_type(4)))  float f32x4;
typedef __attribute__((ext_vector_type(16))) float f32x16;
typedef __attribute__((ext_vector_type(8)))  short short8;
typedef __attribute__((ext_vector_type(4)))  short s16x4;

__device__ __forceinline__ short f2bf(float f) {
  union { float f; uint32_t u; } v; v.f = f;
  uint32_t r = v.u + 0x7FFFu + ((v.u >> 16) & 1u);
  return (short)(r >> 16);
}
__device__ __forceinline__ float bf2f(short s) {
  union { float f; uint32_t u; } v; v.u = ((uint32_t)(uint16_t)s) << 16;
  return v.f;
}
__device__ __forceinline__ unsigned packbf2(float lo, float hi) {
  return (unsigned)(uint16_t)f2bf(lo) | ((unsigned)(uint16_t)f2bf(hi) << 16);
}

#define GLOAD_LDS16(gp, lp) \
  __builtin_amdgcn_global_load_lds((const __attribute__((address_space(1))) void*)(gp), \
                                   (__attribute__((address_space(3))) void*)(lp), 16, 0, 0)

#define BARRIER()  asm volatile("s_barrier" ::: "memory")
#define LGKM0()    asm volatile("s_waitcnt lgkmcnt(0)" ::: "memory")

// ---------------- transpose-convert: fp32 [K][N] -> bf16 [N][K] ----------------
__global__ __launch_bounds__(256) void convT_kernel(const float* __restrict__ src,
    short* __restrict__ dst, int K, int N) {
  __shared__ float t[64][65];
  const int k0 = blockIdx.x * 64, n0 = blockIdx.y * 64;
  const int tr = threadIdx.x >> 4, tc = (threadIdx.x & 15) * 4;
  #pragma unroll
  for (int i = 0; i < 4; ++i) {
    float4 v = *(const float4*)(src + (size_t)(k0 + tr + i * 16) * N + n0 + tc);
    t[tr + i * 16][tc] = v.x; t[tr + i * 16][tc + 1] = v.y;
    t[tr + i * 16][tc + 2] = v.z; t[tr + i * 16][tc + 3] = v.w;
  }
  __syncthreads();
  const int dr = threadIdx.x >> 2, dc = (threadIdx.x & 3) * 16;
  short8 o0, o1;
  #pragma unroll
  for (int j = 0; j < 8; ++j) { o0[j] = f2bf(t[dc + j][dr]); o1[j] = f2bf(t[dc + 8 + j][dr]); }
  short* dp = dst + (size_t)(n0 + dr) * K + k0 + dc;
  *(short8*)dp = o0;
  *(short8*)(dp + 8) = o1;
}

// ---------------- RMSNorm: fp32 in -> bf16 out ----------------
__global__ __launch_bounds__(256) void rmsnorm_kernel(const float* __restrict__ X,
    const float* __restrict__ W, short* __restrict__ Y) {
  int row = blockIdx.x;
  const float4* x4 = (const float4*)(X + (size_t)row * HIDN);
  const float4* w4 = (const float4*)W;
  float4 v0 = x4[2 * threadIdx.x];
  float4 v1 = x4[2 * threadIdx.x + 1];
  float ss = v0.x*v0.x + v0.y*v0.y + v0.z*v0.z + v0.w*v0.w
           + v1.x*v1.x + v1.y*v1.y + v1.z*v1.z + v1.w*v1.w;
  #pragma unroll
  for (int off = 32; off > 0; off >>= 1) ss += __shfl_xor(ss, off, 64);
  __shared__ float red[4];
  if ((threadIdx.x & 63) == 0) red[threadIdx.x >> 6] = ss;
  __syncthreads();
  ss = red[0] + red[1] + red[2] + red[3];
  float rs = rsqrtf(ss * (1.0f / HIDN) + 1e-5f);
  float4 w0 = w4[2 * threadIdx.x], w1 = w4[2 * threadIdx.x + 1];
  short8 o;
  o[0] = f2bf(v0.x * rs * w0.x); o[1] = f2bf(v0.y * rs * w0.y);
  o[2] = f2bf(v0.z * rs * w0.z); o[3] = f2bf(v0.w * rs * w0.w);
  o[4] = f2bf(v1.x * rs * w1.x); o[5] = f2bf(v1.y * rs * w1.y);
  o[6] = f2bf(v1.z * rs * w1.z); o[7] = f2bf(v1.w * rs * w1.w);
  *(short8*)(Y + (size_t)row * HIDN + threadIdx.x * 8) = o;
}

// ============ gemm256: BM=256 x BN, BK=64, 512 thr (8 waves 2Mx4N), =========
// double-buffered LDS, counted-vmcnt pipeline (loads in flight across barriers)
// EPI 0: C bf16 = acc | 1: C f32 = acc + Xf32 | 2: C bf16 = silu(Xbf16)*acc
// EPI 3: C f32 partial (split-K over blockIdx.z)
template<int EPI, int BN>
__global__ __launch_bounds__(512, 2) void gemm256(const short* __restrict__ A,
    const short* __restrict__ BT, void* __restrict__ Cp, const void* __restrict__ Xp,
    int M, int N, int Kfull, int KC) {
  constexpr int NR  = BN / 64;        // B staging rounds (64 rows each)
  constexpr int NFN = BN / 64;        // per-wave N fragments
  constexpr int VM  = 4 + NR;         // loads per K-tile per thread
  __shared__ __align__(16) short As[2][256 * 64];
  __shared__ __align__(16) short Bs[2][BN * 64];
  const int tid = threadIdx.x, lane = tid & 63, w = tid >> 6;
  const int wm = (w >> 2) * 128, wn = (w & 3) * (BN / 4);
  const int l15 = lane & 15, lg = lane >> 4;
  const int brow = blockIdx.x * 256, bcol = blockIdx.y * BN;
  const size_t kbase = (size_t)blockIdx.z * KC;
  const int r8 = lane >> 3;                  // 0..7
  const int gblk = (lane & 7) ^ r8;          // pre-swizzled global 16B block
  const int arow = w * 8 + r8;               // staging row within 64-row round
  const int nt = KC / 64;
  f32x4 acc[8][NFN] = {};

  auto STAGE = [&](int p, int kt) {
    const size_t kc = kbase + (size_t)kt * 64 + gblk * 8;
    #pragma unroll
    for (int j = 0; j < 4; ++j) {
      const short* ga = A + (size_t)(brow + j * 64 + arow) * Kfull + kc;
      GLOAD_LDS16(ga, &As[p][(j * 64 + w * 8) * 64]);
    }
    #pragma unroll
    for (int j = 0; j < NR; ++j) {
      const short* gb = BT + (size_t)(bcol + j * 64 + arow) * Kfull + kc;
      GLOAD_LDS16(gb, &Bs[p][(j * 64 + w * 8) * 64]);
    }
  };

  // prologue: two tiles in flight, wait for the first only
  STAGE(0, 0);
  STAGE(1, 1);
  asm volatile("s_waitcnt vmcnt(%0)" :: "n"(VM) : "memory");
  BARRIER();

  for (int t = 0; t < nt; ++t) {
    const int cur = t & 1;
    #pragma unroll
    for (int kk = 0; kk < 2; ++kk) {
      short8 af[8], bf[NFN];
      #pragma unroll
      for (int m = 0; m < 8; ++m) {
        const int row = wm + m * 16 + l15;
        af[m] = *(const short8*)&As[cur][row * 64 + (((kk * 4 + lg) ^ (l15 & 7)) * 8)];
      }
      #pragma unroll
      for (int n = 0; n < NFN; ++n) {
        const int row = wn + n * 16 + l15;
        bf[n] = *(const short8*)&Bs[cur][row * 64 + (((kk * 4 + lg) ^ (l15 & 7)) * 8)];
      }
      __builtin_amdgcn_s_setprio(1);
      #pragma unroll
      for (int m = 0; m < 8; ++m)
        #pragma unroll
        for (int n = 0; n < NFN; ++n)
          acc[m][n] = __builtin_amdgcn_mfma_f32_16x16x32_bf16(af[m], bf[n], acc[m][n], 0, 0, 0);
      __builtin_amdgcn_s_setprio(0);
    }
    if (t == nt - 1) break;          // last tile: straight to epilogue
    LGKM0();                         // all ds_reads of buf[cur] complete
    BARRIER();                       // B1: safe to overwrite buf[cur]
    if (t + 2 < nt) {
      STAGE(cur, t + 2);             // issue next-next tile
      asm volatile("s_waitcnt vmcnt(%0)" :: "n"(VM) : "memory");  // tile t+1 landed
    } else {
      asm volatile("s_waitcnt vmcnt(0)" ::: "memory");            // drain tail
    }
    BARRIER();                       // B2: tile t+1 ready for all waves
  }

  const int r0 = brow + wm + lg * 4;
  const int c0 = bcol + wn + l15;
  #pragma unroll
  for (int m = 0; m < 8; ++m)
    #pragma unroll
    for (int n = 0; n < NFN; ++n)
      #pragma unroll
      for (int i = 0; i < 4; ++i) {
        const size_t idx = (size_t)(r0 + m * 16 + i) * N + (c0 + n * 16);
        float v = acc[m][n][i];
        if (EPI == 0) ((short*)Cp)[idx] = f2bf(v);
        if (EPI == 1) ((float*)Cp)[idx] = v + ((const float*)Xp)[idx];
        if (EPI == 2) {
          float gf = bf2f(((const short*)Xp)[idx]);
          ((short*)Cp)[idx] = f2bf(gf / (1.f + __expf(-gf)) * v);
        }
        if (EPI == 3) ((float*)Cp)[(size_t)blockIdx.z * M * N + idx] = v;
      }
}

// ---------------- GEMM 128x128 (kept for WO): m97 structure ----------------
template<int EPI>
__global__ __launch_bounds__(256) void gemm_bt(const short* __restrict__ A,
    const short* __restrict__ BT, void* __restrict__ Cp, const void* __restrict__ Xp,
    int M, int N, int Kfull, int KC, int gx) {
  __shared__ __align__(16) short Ass[128 * 64];
  __shared__ __align__(16) short Bss[128 * 64];
  const int tid = threadIdx.x, lane = tid & 63, w = tid >> 6;
  const int wm = (w >> 1) * 64, wn = (w & 1) * 64;
  const int l15 = lane & 15, lg = lane >> 4;
  const int nwg = gridDim.x;
  const int qq = nwg >> 3, xcd = blockIdx.x & 7, off = blockIdx.x >> 3;
  const int wg = xcd * qq + off;
  const int brow = (wg % gx) * 128, bcol = (wg / gx) * 128;
  const size_t kbase = (size_t)blockIdx.y * KC;
  const int srow8 = lane >> 3;
  const int gblk  = (lane & 7) ^ (srow8 & 7);
  f32x4 acc[4][4] = {};

  for (int k0 = 0; k0 < KC; k0 += 64) {
    #pragma unroll
    for (int j = 0; j < 4; ++j) {
      const int rbase = w * 32 + j * 8;
      const int row = rbase + srow8;
      const short* ga = A + (size_t)(brow + row) * Kfull + kbase + k0 + gblk * 8;
      GLOAD_LDS16(ga, Ass + rbase * 64);
      const short* gb = BT + (size_t)(bcol + row) * Kfull + kbase + k0 + gblk * 8;
      GLOAD_LDS16(gb, Bss + rbase * 64);
    }
    __syncthreads();
    #pragma unroll
    for (int kk = 0; kk < 2; ++kk) {
      short8 af[4], bf[4];
      #pragma unroll
      for (int m = 0; m < 4; ++m) {
        const int row = wm + m * 16 + l15;
        af[m] = *(const short8*)&Ass[row * 64 + (((kk * 4 + lg) ^ (l15 & 7)) * 8)];
      }
      #pragma unroll
      for (int n = 0; n < 4; ++n) {
        const int row = wn + n * 16 + l15;
        bf[n] = *(const short8*)&Bss[row * 64 + (((kk * 4 + lg) ^ (l15 & 7)) * 8)];
      }
      #pragma unroll
      for (int m = 0; m < 4; ++m)
        #pragma unroll
        for (int n = 0; n < 4; ++n)
          acc[m][n] = __builtin_amdgcn_mfma_f32_16x16x32_bf16(af[m], bf[n], acc[m][n], 0, 0, 0);
    }
    __syncthreads();
  }

  const int r0 = brow + wm + lg * 4;
  const int c0 = bcol + wn + l15;
  #pragma unroll
  for (int m = 0; m < 4; ++m)
    #pragma unroll
    for (int n = 0; n < 4; ++n)
      #pragma unroll
      for (int i = 0; i < 4; ++i) {
        const size_t idx = (size_t)(r0 + m * 16 + i) * N + (c0 + n * 16);
        float v = acc[m][n][i];
        if (EPI == 0) ((short*)Cp)[idx] = f2bf(v);
        if (EPI == 1) ((float*)Cp)[idx] = v + ((const float*)Xp)[idx];
        if (EPI == 2) {
          float gf = bf2f(((const short*)Xp)[idx]);
          ((short*)Cp)[idx] = f2bf(gf / (1.f + __expf(-gf)) * v);
        }
        if (EPI == 3) ((float*)Cp)[(size_t)blockIdx.y * M * N + idx] = v;
      }
}

// ---------------- RoPE (in-place on bf16 qkv, q + k heads) ----------------
__global__ __launch_bounds__(256) void rope_kernel(short* __restrict__ qkv,
    const float* __restrict__ cosb, const float* __restrict__ sinb) {
  int idx = blockIdx.x * 256 + threadIdx.x;
  int d = idx & 31;
  int hh = (idx >> 5) % (NH + NKV);
  int s = idx / (32 * (NH + NKV));
  int col = (hh < NH) ? hh * HD : HIDN + (hh - NH) * HD;
  short* base = qkv + (size_t)s * QKVLD + col;
  float c  = cosb[s * HD + d];
  float sn = sinb[s * HD + d];
  float x1 = bf2f(base[d]), x2 = bf2f(base[d + 32]);
  base[d]      = f2bf(x1 * c - x2 * sn);
  base[d + 32] = f2bf(x2 * c + x1 * sn);
}

// ---------------- Flash attention: swapped-operand 32x32x16 structure --------
__global__ __launch_bounds__(256) void attn_kernel(const short* __restrict__ QKV,
    short* __restrict__ O) {
  __shared__ __align__(16) short Ks[64][72];
  __shared__ __align__(16) short VTs[64][72];
  const int bid = blockIdx.x;
  const int half = bid >> 8, idx = bid & 255;
  const int h = idx & 31;
  int qt = idx >> 5;
  qt = half ? (15 - qt) : qt;
  const int kvh = h >> 2;
  const int tid = threadIdx.x, lane = tid & 63, w = tid >> 6;
  const int l31 = lane & 31, hi = lane >> 5;
  const int qb = qt * 128 + w * 32;
  const int kcol = HIDN + kvh * HD;
  const int vcol = HIDN + NKV * HD + kvh * HD;

  short8 Qr[4];
  {
    const short* qp = QKV + (size_t)(qb + l31) * QKVLD + h * HD;
    #pragma unroll
    for (int dk = 0; dk < 4; ++dk) {
      short8 qv = *(const short8*)(qp + dk * 16 + hi * 8);
      #pragma unroll
      for (int e = 0; e < 8; ++e) Qr[dk][e] = f2bf(bf2f(qv[e]) * 0.125f);
    }
  }
  float m_ = -3e38f, l_ = 0.f;
  f32x16 o0 = {}, o1 = {};
  const int nt = 2 * qt + 2;
  const int krow = tid >> 2, kcb = (tid & 3) * 16;
  const int vk = tid & 31, vdb = (tid >> 5) * 8;

  for (int t = 0; t < nt; ++t) {
    const int kb = t * 64;
    __syncthreads();
    {
      const short* gk = QKV + (size_t)(kb + krow) * QKVLD + kcol + kcb;
      short8 a = *(const short8*)gk;
      short8 b = *(const short8*)(gk + 8);
      *(short8*)&Ks[krow][kcb] = a;
      *(short8*)&Ks[krow][kcb + 8] = b;
    }
    #pragma unroll
    for (int i = 0; i < 2; ++i) {
      const int k = i * 32 + vk;
      short8 v = *(const short8*)(QKV + (size_t)(kb + k) * QKVLD + vcol + vdb);
      #pragma unroll
      for (int j = 0; j < 8; ++j) VTs[vdb + j][k] = v[j];
    }
    __syncthreads();
    if (kb < qb + 32) {
      f32x16 s[2] = {};
      #pragma unroll
      for (int kt = 0; kt < 2; ++kt)
        #pragma unroll
        for (int dk = 0; dk < 4; ++dk) {
          short8 kf = *(const short8*)&Ks[kt * 32 + l31][dk * 16 + hi * 8];
          s[kt] = __builtin_amdgcn_mfma_f32_32x32x16_bf16(kf, Qr[dk], s[kt], 0, 0, 0);
        }
      if (kb + 63 > qb) {
        const int qg = qb + l31;
        #pragma unroll
        for (int kt = 0; kt < 2; ++kt)
          #pragma unroll
          for (int r = 0; r < 16; ++r) {
            const int kg = kb + kt * 32 + (r & 3) + 8 * (r >> 2) + 4 * hi;
            if (kg > qg) s[kt][r] = -1e30f;
          }
      }
      float pm = s[0][0];
      #pragma unroll
      for (int r = 1; r < 16; ++r) pm = fmaxf(pm, s[0][r]);
      #pragma unroll
      for (int r = 0; r < 16; ++r) pm = fmaxf(pm, s[1][r]);
      pm = fmaxf(pm, __shfl_xor(pm, 32));
      const float mn = fmaxf(m_, pm);
      const float al = __expf(m_ - mn);
      float rsum = 0.f;
      #pragma unroll
      for (int kt = 0; kt < 2; ++kt)
        #pragma unroll
        for (int r = 0; r < 16; ++r) { s[kt][r] = __expf(s[kt][r] - mn); rsum += s[kt][r]; }
      rsum += __shfl_xor(rsum, 32);
      l_ = l_ * al + rsum;
      m_ = mn;
      o0 *= al; o1 *= al;
      unsigned wd[2][8], rw[2][8];
      #pragma unroll
      for (int kt = 0; kt < 2; ++kt)
        #pragma unroll
        for (int i = 0; i < 8; ++i) {
          wd[kt][i] = packbf2(s[kt][2 * i], s[kt][2 * i + 1]);
          rw[kt][i] = (unsigned)__shfl_xor((int)wd[kt][i], 32);
        }
      #pragma unroll
      for (int kt = 0; kt < 2; ++kt) {
        union { unsigned u[4]; short8 s8; } pf0, pf1;
        if (hi) {
          pf0.u[0] = rw[kt][2]; pf0.u[1] = rw[kt][3]; pf0.u[2] = wd[kt][2]; pf0.u[3] = wd[kt][3];
          pf1.u[0] = rw[kt][6]; pf1.u[1] = rw[kt][7]; pf1.u[2] = wd[kt][6]; pf1.u[3] = wd[kt][7];
        } else {
          pf0.u[0] = wd[kt][0]; pf0.u[1] = wd[kt][1]; pf0.u[2] = rw[kt][0]; pf0.u[3] = rw[kt][1];
          pf1.u[0] = wd[kt][4]; pf1.u[1] = wd[kt][5]; pf1.u[2] = rw[kt][4]; pf1.u[3] = rw[kt][5];
        }
        #pragma unroll
        for (int ks = 0; ks < 2; ++ks) {
          const short8 pB = ks ? pf1.s8 : pf0.s8;
          short8 va = *(const short8*)&VTs[l31][kt * 32 + ks * 16 + hi * 8];
          o0 = __builtin_amdgcn_mfma_f32_32x32x16_bf16(va, pB, o0, 0, 0, 0);
          short8 vb = *(const short8*)&VTs[32 + l31][kt * 32 + ks * 16 + hi * 8];
          o1 = __builtin_amdgcn_mfma_f32_32x32x16_bf16(vb, pB, o1, 0, 0, 0);
        }
      }
    }
  }
  const float inv = 1.f / l_;
  short* op = O + (size_t)(qb + l31) * HIDN + h * HD;
  #pragma unroll
  for (int dt = 0; dt < 2; ++dt) {
    const f32x16& o = dt ? o1 : o0;
    #pragma unroll
    for (int g = 0; g < 4; ++g) {
      s16x4 st;
      st[0] = f2bf(o[g * 4 + 0] * inv);
      st[1] = f2bf(o[g * 4 + 1] * inv);
      st[2] = f2bf(o[g * 4 + 2] * inv);
      st[3] = f2bf(o[g * 4 + 3] * inv);
      *(s16x4*)(op + dt * 32 + g * 8 + hi * 4) = st;
    }
  }
}

// ---------------- out += P0 + P1 (split-K reduce) ----------------
__global__ __launch_bounds__(256) void reduce_kernel(float* __restrict__ out,
    const float* __restrict__ P) {
  const size_t n = (size_t)S_LEN * HIDN;
  size_t i = ((size_t)blockIdx.x * 256 + threadIdx.x) * 4;
  float4 o = *(float4*)(out + i);
  float4 a = *(const float4*)(P + i);
  float4 b = *(const float4*)(P + n + i);
  o.x += a.x + b.x; o.y += a.y + b.y; o.z += a.z + b.z; o.w += a.w + b.w;
  *(float4*)(out + i) = o;
}

extern "C" void kernel_launch(void* const* d_in, const int* in_sizes, int n_in,
                              void* d_out, int out_size, void* d_ws, size_t ws_size,
                              hipStream_t stream) {
  const float* hs   = (const float*)d_in[0];
  const float* cosb = (const float*)d_in[1];
  const float* sinb = (const float*)d_in[2];
  const float* wq   = (const float*)d_in[3];
  const float* wk   = (const float*)d_in[4];
  const float* wv   = (const float*)d_in[5];
  const float* wo   = (const float*)d_in[6];
  const float* wln1 = (const float*)d_in[7];
  const float* wln2 = (const float*)d_in[8];
  const float* wg   = (const float*)d_in[9];
  const float* wu   = (const float*)d_in[10];
  const float* wd   = (const float*)d_in[11];
  float* out = (float*)d_out;
  char* ws = (char*)d_ws;
  const size_t MB = 1024 * 1024;
  short* xn    = (short*)(ws);             //  8 MB bf16 [2048][2048]
  short* y     = (short*)(ws + 8 * MB);    //  8 MB
  short* attnO = (short*)(ws + 16 * MB);   //  8 MB
  short* qkv   = (short*)(ws + 24 * MB);   // 12.6 MB bf16 [2048][3072]
  short* g     = (short*)(ws + 37 * MB);   // 32 MB bf16 [2048][8192]
  short* Wbuf  = (short*)(ws + 69 * MB);   // 32 MB time-shared transposed weights
  float* P     = (float*)(ws);             // 32 MB split-K partials (aliases dead bufs)

  convT_kernel<<<dim3(32, 32), 256, 0, stream>>>(wq, Wbuf, HIDN, NH * HD);
  convT_kernel<<<dim3(32, 8),  256, 0, stream>>>(wk, Wbuf + (size_t)2048 * HIDN, HIDN, NKV * HD);
  convT_kernel<<<dim3(32, 8),  256, 0, stream>>>(wv, Wbuf + (size_t)2560 * HIDN, HIDN, NKV * HD);
  rmsnorm_kernel<<<S_LEN, 256, 0, stream>>>(hs, wln1, xn);
  gemm256<0, 128><<<dim3(8, 24, 1), 512, 0, stream>>>(xn, Wbuf, qkv, nullptr, S_LEN, QKVN, HIDN, HIDN);
  convT_kernel<<<dim3(32, 32), 256, 0, stream>>>(wo, Wbuf, NH * HD, HIDN);
  rope_kernel<<<(S_LEN * (NH + NKV) * 32) / 256, 256, 0, stream>>>(qkv, cosb, sinb);
  attn_kernel<<<NH * (S_LEN / 128), 256, 0, stream>>>(qkv, attnO);
  gemm_bt<1><<<dim3(16 * 16, 1), 256, 0, stream>>>(attnO, Wbuf, out, hs, S_LEN, HIDN, NH * HD, NH * HD, 16);
  rmsnorm_kernel<<<S_LEN, 256, 0, stream>>>(out, wln2, y);
  convT_kernel<<<dim3(32, 128), 256, 0, stream>>>(wg, Wbuf, HIDN, FFN);
  gemm256<0, 256><<<dim3(8, 32, 1), 512, 0, stream>>>(y, Wbuf, g, nullptr, S_LEN, FFN, HIDN, HIDN);
  convT_kernel<<<dim3(32, 128), 256, 0, stream>>>(wu, Wbuf, HIDN, FFN);
  gemm256<2, 256><<<dim3(8, 32, 1), 512, 0, stream>>>(y, Wbuf, g, g, S_LEN, FFN, HIDN, HIDN);
  convT_kernel<<<dim3(128, 32), 256, 0, stream>>>(wd, Wbuf, FFN, HIDN);
  gemm256<3, 128><<<dim3(8, 16, 2), 512, 0, stream>>>(g, Wbuf, P, nullptr, S_LEN, HIDN, FFN, FFN / 2);
  reduce_kernel<<<(S_LEN * HIDN) / 1024, 256, 0, stream>>>(out, P);
}